// Round 5
// baseline (101.962 us; speedup 1.0000x reference)
//
#include <hip/hip_runtime.h>
#include <hip/hip_fp16.h>

#define HDIM 256
#define LDIM 384
#define BDIM 2
#define ADIM 14

typedef __attribute__((ext_vector_type(8))) _Float16 f16x8;
typedef __attribute__((ext_vector_type(2))) _Float16 f16x2;
typedef __attribute__((ext_vector_type(4))) float f32x4;

static __device__ __forceinline__ unsigned pack_f16(float x, float y) {
    f16x2 t = {(_Float16)x, (_Float16)y};     // x -> low 16
    union { f16x2 v; unsigned u; } c; c.v = t;
    return c.u;
}

// relu(a+b) on packed f16 pairs -> v_pk_add_f16 + v_pk_max_f16
static __device__ __forceinline__ unsigned relu_add(unsigned a, unsigned b) {
    union { unsigned u; f16x2 v; } ua, ub, ur;
    ua.u = a; ub.u = b;
    const f16x2 z = {(_Float16)0.f, (_Float16)0.f};
    ur.v = __builtin_elementwise_max(ua.v + ub.v, z);
    return ur.u;
}

// ---------------------------------------------------------------------------
// Kernel 1: LDS-free MFMA front GEMM.
// One wave per 16x16 output tile of C(768 x 512) = h @ [Wx; Ux]^T + bias.
//   A = weight rows (channels), B = h rows (residues), K = 256 (8 chunks).
//   D: col=lane&15 -> residue-in-tile, row=quad*4+r -> channel.
// Output: hwP[row][h2] / huP[row][h2] packed f16 channel-pairs (row = b*L+i).
// Block 384 packs Tx_w -> txP[16][128] f16 pairs instead.
// ---------------------------------------------------------------------------
__global__ __launch_bounds__(256) void k_front(
    const float* __restrict__ h,
    const float* __restrict__ Wx_w, const float* __restrict__ Wx_b,
    const float* __restrict__ Ux_w, const float* __restrict__ Ux_b,
    const float* __restrict__ Tx_w,
    unsigned* __restrict__ hwP, unsigned* __restrict__ huP,
    unsigned* __restrict__ txP)
{
    const int tid = threadIdx.x;
    if (blockIdx.x == 384) {                    // Tx_w packer block
        for (int idx = tid; idx < 16 * 128; idx += 256) {
            const int a = idx >> 7, k2 = idx & 127;
            unsigned v = 0;
            if (a < ADIM) {
                const float2 tw = *(const float2*)&Tx_w[a * HDIM + 2 * k2];
                v = pack_f16(tw.x, tw.y);
            }
            txP[idx] = v;
        }
        return;
    }
    const int w = tid >> 6, lane = tid & 63;
    const int n = lane & 15, quad = lane >> 4;
    const int g = blockIdx.x * 4 + w;           // 0..1535
    const int ctile = g & 31;                   // 32 col-tiles (0-15 Wx, 16-31 Ux)
    const int rtile = g >> 5;                   // 48 row-tiles

    const int arow = (ctile & 15) * 16 + n;     // channel row for A operand
    const float* __restrict__ Arow = (ctile < 16) ? &Wx_w[arow * HDIM]
                                                  : &Ux_w[arow * HDIM];
    const float* __restrict__ Brow = &h[(rtile * 16 + n) * HDIM];

    f32x4 acc = {0.f, 0.f, 0.f, 0.f};
    #pragma unroll
    for (int kc = 0; kc < 8; ++kc) {
        const int ko = kc * 32 + quad * 8;
        const float4 a0 = *(const float4*)&Arow[ko];
        const float4 a1 = *(const float4*)&Arow[ko + 4];
        const float4 b0 = *(const float4*)&Brow[ko];
        const float4 b1 = *(const float4*)&Brow[ko + 4];
        union { unsigned u[4]; f16x8 v; } af, bf;
        af.u[0] = pack_f16(a0.x, a0.y); af.u[1] = pack_f16(a0.z, a0.w);
        af.u[2] = pack_f16(a1.x, a1.y); af.u[3] = pack_f16(a1.z, a1.w);
        bf.u[0] = pack_f16(b0.x, b0.y); bf.u[1] = pack_f16(b0.z, b0.w);
        bf.u[2] = pack_f16(b1.x, b1.y); bf.u[3] = pack_f16(b1.z, b1.w);
        acc = __builtin_amdgcn_mfma_f32_16x16x32_f16(af.v, bf.v, acc, 0, 0, 0);
    }

    const int row = rtile * 16 + n;                 // flat residue row (b*L+i)
    const int c0 = (ctile & 15) * 16 + quad * 4;    // first channel this lane holds
    const float4 bias = (ctile < 16) ? *(const float4*)&Wx_b[c0]
                                     : *(const float4*)&Ux_b[c0];
    uint2 pv;
    pv.x = pack_f16(acc[0] + bias.x, acc[1] + bias.y);
    pv.y = pack_f16(acc[2] + bias.z, acc[3] + bias.w);
    unsigned* __restrict__ dst = (ctile < 16) ? hwP : huP;
    *(uint2*)&dst[row * 128 + (ctile & 15) * 8 + quad * 2] = pv;
}

// ---------------------------------------------------------------------------
// Kernel 2: one block (384 thr) per (b,i).
// gate = relu(hw_i + hu_j) @ Tx_w^T via f16 MFMA; A-frag built in-register
// from one dwordx4 per (tile, k-chunk): 2 VALU per f16-pair (pk_add+pk_max).
// Epilogue: per-lane j-partials -> 24-group LDS combine -> 42-lane finalize.
// ---------------------------------------------------------------------------
__global__ __launch_bounds__(384) void k_main(
    const unsigned* __restrict__ hwP, const unsigned* __restrict__ huP,
    const unsigned* __restrict__ txP,
    const float* __restrict__ X, const int* __restrict__ mask,
    const float* __restrict__ Tx_b,
    float* __restrict__ out)
{
    __shared__ float m_lds[LDIM];
    __shared__ float part2[24 * 16 * 4];   // [group][a][{s2x,s2y,s2z,s1}]
    __shared__ float part_m[24];

    const int i = blockIdx.x, b = blockIdx.y;
    const int tid = threadIdx.x;
    const int w = tid >> 6, lane = tid & 63;
    const int n = lane & 15, quad = lane >> 4;

    m_lds[tid] = (float)mask[b * LDIM + tid];
    __syncthreads();

    const unsigned* __restrict__ hwr = &hwP[(b * LDIM + i) * 128];
    const unsigned* __restrict__ hub = &huP[b * LDIM * 128];
    const unsigned* __restrict__ txr = &txP[n * 128];

    f32x4 acc[4];
    #pragma unroll
    for (int t = 0; t < 4; ++t) acc[t] = (f32x4){0.f, 0.f, 0.f, 0.f};

    #pragma unroll 4
    for (int kc = 0; kc < 8; ++kc) {
        const int ko = kc * 16 + quad * 4;          // h2 offset of this lane's k-slice
        const uint4 hw4 = *(const uint4*)&hwr[ko];  // broadcast within quad-group
        const uint4 tx4 = *(const uint4*)&txr[ko];
        union { unsigned u[4]; f16x8 v; } bfrag;
        bfrag.u[0] = tx4.x; bfrag.u[1] = tx4.y;
        bfrag.u[2] = tx4.z; bfrag.u[3] = tx4.w;
        #pragma unroll
        for (int t = 0; t < 4; ++t) {
            const int j = (w * 4 + t) * 16 + n;     // A row (j) for this lane
            const uint4 hu4 = *(const uint4*)&hub[j * 128 + ko];
            union { unsigned u[4]; f16x8 v; } af;
            af.u[0] = relu_add(hw4.x, hu4.x);
            af.u[1] = relu_add(hw4.y, hu4.y);
            af.u[2] = relu_add(hw4.z, hu4.z);
            af.u[3] = relu_add(hw4.w, hu4.w);
            acc[t] = __builtin_amdgcn_mfma_f32_16x16x32_f16(af.v, bfrag.v, acc[t], 0, 0, 0);
        }
    }

    // per-lane partials over its 16 j's (a = n); D row=quad*4+r -> j-in-tile
    float s1 = 0.f, s2x = 0.f, s2y = 0.f, s2z = 0.f, pm = 0.f;
    if (n < ADIM) {
        const float txb = Tx_b[n];
        #pragma unroll
        for (int t = 0; t < 4; ++t) {
            #pragma unroll
            for (int r = 0; r < 4; ++r) {
                const int jd = (w * 4 + t) * 16 + quad * 4 + r;
                const float m = m_lds[jd];
                const float g = acc[t][r] + txb;
                const float mg = m * g;
                const float* __restrict__ Xp = &X[((b * LDIM + jd) * ADIM + n) * 3];
                s1 += mg;
                s2x = fmaf(mg, Xp[0], s2x);
                s2y = fmaf(mg, Xp[1], s2y);
                s2z = fmaf(mg, Xp[2], s2z);
                pm += m;
            }
        }
    }
    {
        f32x4 sv = {s2x, s2y, s2z, s1};
        *(f32x4*)&part2[((w * 4 + quad) * 16 + n) * 4] = sv;
    }
    if (n == 0) part_m[w * 4 + quad] = pm;
    __syncthreads();

    if (tid < 42) {
        const int a = tid / 3, c = tid % 3;
        float S2 = 0.f, S1 = 0.f, msum = 0.f;
        #pragma unroll 4
        for (int g = 0; g < 24; ++g) {
            const float* __restrict__ p = &part2[(g * 16 + a) * 4];
            S2 += p[c]; S1 += p[3]; msum += part_m[g];
        }
        const float denom = 1e-6f + msum;
        const int idx = ((b * LDIM + i) * ADIM + a) * 3 + c;
        const float xi = X[idx];
        float f = (xi * S1 - S2) / denom;
        f = fminf(fmaxf(f, -20.f), 20.f);
        out[idx] = xi + f;
    }
}

extern "C" void kernel_launch(void* const* d_in, const int* in_sizes, int n_in,
                              void* d_out, int out_size, void* d_ws, size_t ws_size,
                              hipStream_t stream) {
    (void)in_sizes; (void)n_in; (void)out_size; (void)ws_size;
    const float* h    = (const float*)d_in[0];
    const float* X    = (const float*)d_in[1];
    const int*   mask = (const int*)  d_in[2];
    const float* Wx_w = (const float*)d_in[3];
    const float* Wx_b = (const float*)d_in[4];
    const float* Ux_w = (const float*)d_in[5];
    const float* Ux_b = (const float*)d_in[6];
    const float* Tx_w = (const float*)d_in[7];
    const float* Tx_b = (const float*)d_in[8];
    float* out = (float*)d_out;

    unsigned* hwP = (unsigned*)d_ws;                   // [768][128] f16-pairs
    unsigned* huP = hwP + BDIM * LDIM * (HDIM / 2);    // [768][128] f16-pairs
    unsigned* txP = huP + BDIM * LDIM * (HDIM / 2);    // [16][128]  f16-pairs

    k_front<<<385, 256, 0, stream>>>(h, Wx_w, Wx_b, Ux_w, Ux_b, Tx_w, hwP, huP, txP);
    k_main<<<dim3(LDIM, BDIM), 384, 0, stream>>>(hwP, huP, txP, X, mask, Tx_b, out);
}

// Round 6
// 101.390 us; speedup vs baseline: 1.0056x; 1.0056x over previous
//
#include <hip/hip_runtime.h>
#include <hip/hip_fp16.h>

#define HDIM 256
#define LDIM 384
#define BDIM 2
#define ADIM 14

typedef __attribute__((ext_vector_type(8))) _Float16 f16x8;
typedef __attribute__((ext_vector_type(2))) _Float16 f16x2;
typedef __attribute__((ext_vector_type(4))) float f32x4;

static __device__ __forceinline__ unsigned pack_f16(float x, float y) {
    f16x2 t = {(_Float16)x, (_Float16)y};     // x -> low 16
    union { f16x2 v; unsigned u; } c; c.v = t;
    return c.u;
}

// relu(a+b) on packed f16 pairs -> v_pk_add_f16 + v_pk_max_f16
static __device__ __forceinline__ unsigned relu_add(unsigned a, unsigned b) {
    union { unsigned u; f16x2 v; } ua, ub, ur;
    ua.u = a; ub.u = b;
    const f16x2 z = {(_Float16)0.f, (_Float16)0.f};
    ur.v = __builtin_elementwise_max(ua.v + ub.v, z);
    return ur.u;
}

// ---------------------------------------------------------------------------
// Kernel 1: LDS-free MFMA front GEMM (unchanged from round 5).
// One wave per 16x16 output tile of C(768 x 512) = h @ [Wx; Ux]^T + bias.
// Output: hwP/huP[row][h2] packed f16 channel-pairs (row = b*L+i).
// Block 384 packs Tx_w -> txP[16][128] f16 pairs instead.
// ---------------------------------------------------------------------------
__global__ __launch_bounds__(256) void k_front(
    const float* __restrict__ h,
    const float* __restrict__ Wx_w, const float* __restrict__ Wx_b,
    const float* __restrict__ Ux_w, const float* __restrict__ Ux_b,
    const float* __restrict__ Tx_w,
    unsigned* __restrict__ hwP, unsigned* __restrict__ huP,
    unsigned* __restrict__ txP)
{
    const int tid = threadIdx.x;
    if (blockIdx.x == 384) {                    // Tx_w packer block
        for (int idx = tid; idx < 16 * 128; idx += 256) {
            const int a = idx >> 7, k2 = idx & 127;
            unsigned v = 0;
            if (a < ADIM) {
                const float2 tw = *(const float2*)&Tx_w[a * HDIM + 2 * k2];
                v = pack_f16(tw.x, tw.y);
            }
            txP[idx] = v;
        }
        return;
    }
    const int w = tid >> 6, lane = tid & 63;
    const int n = lane & 15, quad = lane >> 4;
    const int g = blockIdx.x * 4 + w;           // 0..1535
    const int ctile = g & 31;                   // 0-15 Wx, 16-31 Ux
    const int rtile = g >> 5;                   // 48 row-tiles

    const int arow = (ctile & 15) * 16 + n;
    const float* __restrict__ Arow = (ctile < 16) ? &Wx_w[arow * HDIM]
                                                  : &Ux_w[arow * HDIM];
    const float* __restrict__ Brow = &h[(rtile * 16 + n) * HDIM];

    f32x4 acc = {0.f, 0.f, 0.f, 0.f};
    #pragma unroll
    for (int kc = 0; kc < 8; ++kc) {
        const int ko = kc * 32 + quad * 8;
        const float4 a0 = *(const float4*)&Arow[ko];
        const float4 a1 = *(const float4*)&Arow[ko + 4];
        const float4 b0 = *(const float4*)&Brow[ko];
        const float4 b1 = *(const float4*)&Brow[ko + 4];
        union { unsigned u[4]; f16x8 v; } af, bf;
        af.u[0] = pack_f16(a0.x, a0.y); af.u[1] = pack_f16(a0.z, a0.w);
        af.u[2] = pack_f16(a1.x, a1.y); af.u[3] = pack_f16(a1.z, a1.w);
        bf.u[0] = pack_f16(b0.x, b0.y); bf.u[1] = pack_f16(b0.z, b0.w);
        bf.u[2] = pack_f16(b1.x, b1.y); bf.u[3] = pack_f16(b1.z, b1.w);
        acc = __builtin_amdgcn_mfma_f32_16x16x32_f16(af.v, bf.v, acc, 0, 0, 0);
    }

    const int row = rtile * 16 + n;
    const int c0 = (ctile & 15) * 16 + quad * 4;
    const float4 bias = (ctile < 16) ? *(const float4*)&Wx_b[c0]
                                     : *(const float4*)&Ux_b[c0];
    uint2 pv;
    pv.x = pack_f16(acc[0] + bias.x, acc[1] + bias.y);
    pv.y = pack_f16(acc[2] + bias.z, acc[3] + bias.w);
    unsigned* __restrict__ dst = (ctile < 16) ? hwP : huP;
    *(uint2*)&dst[row * 128 + (ctile & 15) * 8 + quad * 2] = pv;
}

// ---------------------------------------------------------------------------
// Kernel 2: one block (384 thr) per (b, i-pair). The hu4 load stream is shared
// by both i's. X[b] (63 KB) staged in LDS so the epilogue gather is LDS-local
// (global version cost ~15 us of L1 line-serialization).
// ---------------------------------------------------------------------------
__global__ __launch_bounds__(384) void k_main(
    const unsigned* __restrict__ hwP, const unsigned* __restrict__ huP,
    const unsigned* __restrict__ txP,
    const float* __restrict__ X, const int* __restrict__ mask,
    const float* __restrict__ Tx_b,
    float* __restrict__ out)
{
    __shared__ float Xl[LDIM * 42];        // X[b] flat: [j][a][c], 63 KB
    __shared__ float m_lds[LDIM];
    __shared__ float part2[2][24 * 16 * 4]; // [i][group][a][{s2x,s2y,s2z,s1}]
    __shared__ float part_m[24];

    const int i0 = blockIdx.x * 2, i1 = i0 + 1;
    const int b  = blockIdx.y;
    const int tid = threadIdx.x;
    const int w = tid >> 6, lane = tid & 63;
    const int n = lane & 15, quad = lane >> 4;

    {   // stage X[b] -> LDS, coalesced float4 (4032 vec4s)
        const float4* __restrict__ Xg4 = (const float4*)&X[b * (LDIM * 42)];
        float4* __restrict__ Xl4 = (float4*)Xl;
        for (int idx = tid; idx < LDIM * 42 / 4; idx += 384) Xl4[idx] = Xg4[idx];
        m_lds[tid] = (float)mask[b * LDIM + tid];
    }
    __syncthreads();

    const unsigned* __restrict__ hwr0 = &hwP[(b * LDIM + i0) * 128];
    const unsigned* __restrict__ hwr1 = &hwP[(b * LDIM + i1) * 128];
    const unsigned* __restrict__ hub  = &huP[b * LDIM * 128];
    const unsigned* __restrict__ txr  = &txP[n * 128];

    f32x4 acc0[4], acc1[4];
    #pragma unroll
    for (int t = 0; t < 4; ++t) {
        acc0[t] = (f32x4){0.f, 0.f, 0.f, 0.f};
        acc1[t] = (f32x4){0.f, 0.f, 0.f, 0.f};
    }

    #pragma unroll 2
    for (int kc = 0; kc < 8; ++kc) {
        const int ko = kc * 16 + quad * 4;
        const uint4 hwa = *(const uint4*)&hwr0[ko];
        const uint4 hwb = *(const uint4*)&hwr1[ko];
        const uint4 tx4 = *(const uint4*)&txr[ko];
        union { unsigned u[4]; f16x8 v; } bfrag;
        bfrag.u[0] = tx4.x; bfrag.u[1] = tx4.y;
        bfrag.u[2] = tx4.z; bfrag.u[3] = tx4.w;
        #pragma unroll
        for (int t = 0; t < 4; ++t) {
            const int j = (w * 4 + t) * 16 + n;
            const uint4 hu4 = *(const uint4*)&hub[j * 128 + ko];   // shared by i0,i1
            union { unsigned u[4]; f16x8 v; } af;
            af.u[0] = relu_add(hwa.x, hu4.x);
            af.u[1] = relu_add(hwa.y, hu4.y);
            af.u[2] = relu_add(hwa.z, hu4.z);
            af.u[3] = relu_add(hwa.w, hu4.w);
            acc0[t] = __builtin_amdgcn_mfma_f32_16x16x32_f16(af.v, bfrag.v, acc0[t], 0, 0, 0);
            af.u[0] = relu_add(hwb.x, hu4.x);
            af.u[1] = relu_add(hwb.y, hu4.y);
            af.u[2] = relu_add(hwb.z, hu4.z);
            af.u[3] = relu_add(hwb.w, hu4.w);
            acc1[t] = __builtin_amdgcn_mfma_f32_16x16x32_f16(af.v, bfrag.v, acc1[t], 0, 0, 0);
        }
    }

    // per-lane partials over this lane's 16 j's (a = n); D row = quad*4+r -> j
    float pm = 0.f;
    #pragma unroll
    for (int ii = 0; ii < 2; ++ii) {
        const f32x4* acc = ii ? acc1 : acc0;
        float s1 = 0.f, s2x = 0.f, s2y = 0.f, s2z = 0.f;
        if (n < ADIM) {
            const float txb = Tx_b[n];
            #pragma unroll
            for (int t = 0; t < 4; ++t) {
                #pragma unroll
                for (int r = 0; r < 4; ++r) {
                    const int jd = (w * 4 + t) * 16 + quad * 4 + r;
                    const float m = m_lds[jd];
                    const float g = acc[t][r] + txb;
                    const float mg = m * g;
                    const float* __restrict__ Xp = &Xl[jd * 42 + n * 3];
                    s1 += mg;
                    s2x = fmaf(mg, Xp[0], s2x);
                    s2y = fmaf(mg, Xp[1], s2y);
                    s2z = fmaf(mg, Xp[2], s2z);
                    if (ii == 0) pm += m;
                }
            }
        }
        f32x4 sv = {s2x, s2y, s2z, s1};
        *(f32x4*)&part2[ii][((w * 4 + quad) * 16 + n) * 4] = sv;
    }
    if (n == 0) part_m[w * 4 + quad] = pm;
    __syncthreads();

    // finalize: threads 0..41 -> i0, threads 64..105 -> i1 (separate waves)
    int ii = -1, t42 = 0;
    if (tid < 42)                    { ii = 0; t42 = tid; }
    else if (tid >= 64 && tid < 106) { ii = 1; t42 = tid - 64; }
    if (ii >= 0) {
        const int a = t42 / 3, c = t42 % 3;
        const int i = ii ? i1 : i0;
        float S2 = 0.f, S1 = 0.f, msum = 0.f;
        #pragma unroll 4
        for (int g = 0; g < 24; ++g) {
            const float* __restrict__ p = &part2[ii][(g * 16 + a) * 4];
            S2 += p[c]; S1 += p[3]; msum += part_m[g];
        }
        const float denom = 1e-6f + msum;
        const float xi = Xl[i * 42 + t42];
        float f = (xi * S1 - S2) / denom;
        f = fminf(fmaxf(f, -20.f), 20.f);
        out[((b * LDIM + i) * ADIM + a) * 3 + c] = xi + f;
    }
}

extern "C" void kernel_launch(void* const* d_in, const int* in_sizes, int n_in,
                              void* d_out, int out_size, void* d_ws, size_t ws_size,
                              hipStream_t stream) {
    (void)in_sizes; (void)n_in; (void)out_size; (void)ws_size;
    const float* h    = (const float*)d_in[0];
    const float* X    = (const float*)d_in[1];
    const int*   mask = (const int*)  d_in[2];
    const float* Wx_w = (const float*)d_in[3];
    const float* Wx_b = (const float*)d_in[4];
    const float* Ux_w = (const float*)d_in[5];
    const float* Ux_b = (const float*)d_in[6];
    const float* Tx_w = (const float*)d_in[7];
    const float* Tx_b = (const float*)d_in[8];
    float* out = (float*)d_out;

    unsigned* hwP = (unsigned*)d_ws;                   // [768][128] f16-pairs
    unsigned* huP = hwP + BDIM * LDIM * (HDIM / 2);    // [768][128] f16-pairs
    unsigned* txP = huP + BDIM * LDIM * (HDIM / 2);    // [16][128]  f16-pairs

    k_front<<<385, 256, 0, stream>>>(h, Wx_w, Wx_b, Ux_w, Ux_b, Tx_w, hwP, huP, txP);
    k_main<<<dim3(LDIM / 2, BDIM), 384, 0, stream>>>(hwP, huP, txP, X, mask, Tx_b, out);
}